// Round 1
// baseline (1077.720 us; speedup 1.0000x reference)
//
#include <hip/hip_runtime.h>
#include <math.h>

#define N_NODES 50000
#define F_DIM 256
#define NE 1000000
#define N_HEADS 8
#define N_UNITS 32
#define OUT_DIM 64

// ---------------------------------------------------------------------------
// row_start[i] = lower_bound(src, i); src is sorted, so edges of node i are
// [row_start[i], row_start[i+1]).
// ---------------------------------------------------------------------------
__global__ void row_start_kernel(const int* __restrict__ edges,
                                 int* __restrict__ row_start) {
    int i = blockIdx.x * blockDim.x + threadIdx.x;
    if (i > N_NODES) return;
    if (i == N_NODES) { row_start[N_NODES] = NE; return; }
    int lo = 0, hi = NE;
    while (lo < hi) {
        int mid = (lo + hi) >> 1;
        if (edges[2 * mid] < i) lo = mid + 1; else hi = mid;
    }
    row_start[i] = lo;
}

// ---------------------------------------------------------------------------
// Y[N x M] = X[N x 256] @ W + bias (optional) with optional relu.
// W addressing: W[k][col] at W[k*strideK + (col>>5)*strideH + (col&31)]
//   Wp  (256,256) row-major: strideK=256, strideH=32
//   Wk[l] (8,256,32) head-major: strideK=32, strideH=8192
//   Wo  (256,64) row-major: strideK=64, strideH=32
// Block: 256 threads, 16 rows x M cols, each thread 4 cols x RPT rows.
// ---------------------------------------------------------------------------
template <int M>
__global__ __launch_bounds__(256) void matmul_kernel(
    const float* __restrict__ X, const float* __restrict__ W,
    const float* __restrict__ bias, float* __restrict__ Y,
    int strideK, int strideH, int relu_flag) {
    constexpr int RB = 16;            // rows per block
    constexpr int CG = M / 4;         // thread-groups across cols
    constexpr int G = 256 / CG;       // row groups
    constexpr int RPT = RB / G;       // rows per thread
    __shared__ float xs[256][20];     // [k][r], pad 20 keeps 16B align + spreads banks

    const int tid = threadIdx.x;
    const long row0 = (long)blockIdx.x * RB;

    // stage + transpose X tile: k = tid, r = it  (coalesced global reads)
#pragma unroll
    for (int it = 0; it < RB; ++it) {
        xs[tid][it] = X[(row0 + it) * F_DIM + tid];
    }
    __syncthreads();

    const int col0 = (tid % CG) * 4;
    const int rg = tid / CG;
    const int r0 = rg * RPT;
    const float* wp = W + (col0 >> 5) * strideH + (col0 & 31);

    float acc[RPT][4];
#pragma unroll
    for (int j = 0; j < RPT; ++j)
#pragma unroll
        for (int c = 0; c < 4; ++c) acc[j][c] = 0.f;

#pragma unroll 4
    for (int k = 0; k < F_DIM; ++k) {
        const float4 w4 = *(const float4*)(wp + (long)k * strideK);
        float xv[RPT];
#pragma unroll
        for (int j = 0; j < RPT; ++j) xv[j] = xs[k][r0 + j];
#pragma unroll
        for (int j = 0; j < RPT; ++j) {
            acc[j][0] += xv[j] * w4.x;
            acc[j][1] += xv[j] * w4.y;
            acc[j][2] += xv[j] * w4.z;
            acc[j][3] += xv[j] * w4.w;
        }
    }

    float b[4] = {0.f, 0.f, 0.f, 0.f};
    if (bias) {
#pragma unroll
        for (int c = 0; c < 4; ++c) b[c] = bias[col0 + c];
    }
#pragma unroll
    for (int j = 0; j < RPT; ++j) {
        float4 o;
        o.x = acc[j][0] + b[0];
        o.y = acc[j][1] + b[1];
        o.z = acc[j][2] + b[2];
        o.w = acc[j][3] + b[3];
        if (relu_flag) {
            o.x = fmaxf(o.x, 0.f); o.y = fmaxf(o.y, 0.f);
            o.z = fmaxf(o.z, 0.f); o.w = fmaxf(o.w, 0.f);
        }
        *(float4*)(&Y[(row0 + r0 + j) * M + col0]) = o;
    }
}

// ---------------------------------------------------------------------------
// alpha_src[i,h] = xt[i, 32h:32h+32] . Wa_l[h, 0:32]
// alpha_dst[i,h] = xt[i, 32h:32h+32] . Wa_l[h, 32:64]
// one block (256 thr) per node; reduce within 32-lane groups.
// ---------------------------------------------------------------------------
__global__ __launch_bounds__(256) void alpha_kernel(
    const float* __restrict__ xt, const float* __restrict__ Wa_l,
    float* __restrict__ a_src, float* __restrict__ a_dst) {
    const int i = blockIdx.x;
    const int tid = threadIdx.x;
    const int h = tid >> 5, u = tid & 31;
    const float v = xt[(long)i * F_DIM + tid];
    float p1 = v * Wa_l[h * 64 + u];
    float p2 = v * Wa_l[h * 64 + 32 + u];
#pragma unroll
    for (int off = 16; off > 0; off >>= 1) {
        p1 += __shfl_down(p1, off, 32);
        p2 += __shfl_down(p2, off, 32);
    }
    if (u == 0) {
        a_src[i * N_HEADS + h] = p1;
        a_dst[i * N_HEADS + h] = p2;
    }
}

// ---------------------------------------------------------------------------
// Per-node edge aggregation, one block per node i (src segment):
//   s_e = exp(clip(leaky_relu((a_src[i,h]+a_dst[dst,h])*ew_e), -2, 2))
//   acc = sum_e xt[dst_e]*s_e ; ssum = sum_e s_e
//   x[i] += relu(acc/ssum)   (in-place residual; xt is a separate buffer)
// ---------------------------------------------------------------------------
__global__ __launch_bounds__(256) void edge_kernel(
    const int* __restrict__ edges, const float* __restrict__ ew,
    const int* __restrict__ row_start, const float* __restrict__ xt,
    const float* __restrict__ a_src, const float* __restrict__ a_dst,
    float* __restrict__ x) {
    const int i = blockIdx.x;
    const int tid = threadIdx.x;
    const int h = tid >> 5;
    const float asrc = a_src[i * N_HEADS + h];
    const int e0 = row_start[i], e1 = row_start[i + 1];
    float acc = 0.f, ssum = 0.f;
    for (int e = e0; e < e1; ++e) {
        const int d = edges[2 * e + 1];
        const float w = ew[e];
        const float ad = a_dst[d * N_HEADS + h];
        float sp = (asrc + ad) * w;
        sp = (sp >= 0.f) ? sp : 0.2f * sp;       // leaky_relu(0.2)
        sp = fminf(fmaxf(sp, -2.f), 2.f);        // clip
        const float s = __expf(sp);
        acc += xt[(long)d * F_DIM + tid] * s;
        ssum += s;
    }
    float v = (ssum > 0.f) ? (acc / ssum) : 0.f; // empty segment -> 0
    v = fmaxf(v, 0.f);                           // relu on head output
    const long idx = (long)i * F_DIM + tid;
    x[idx] = x[idx] + v;                         // residual
}

// ---------------------------------------------------------------------------
extern "C" void kernel_launch(void* const* d_in, const int* in_sizes, int n_in,
                              void* d_out, int out_size, void* d_ws,
                              size_t ws_size, hipStream_t stream) {
    const float* node_states = (const float*)d_in[0];  // (1,N,256)
    const int* edges = (const int*)d_in[1];            // (1,E,2) [src,dst]
    const float* ew = (const float*)d_in[2];           // (1,E)
    /* d_in[3] pos_cls: unused by reference */
    const float* Wp = (const float*)d_in[4];           // (256,256)
    const float* bp = (const float*)d_in[5];           // (256,)
    const float* Wk = (const float*)d_in[6];           // (2,8,256,32)
    const float* Wa = (const float*)d_in[7];           // (2,8,64,1)
    const float* Wo = (const float*)d_in[8];           // (256,64)
    const float* bo = (const float*)d_in[9];           // (64,)
    float* out = (float*)d_out;                        // (1,N,64)

    float* ws = (float*)d_ws;
    float* x = ws;                                   // N*256
    float* xt = ws + (size_t)N_NODES * F_DIM;        // N*256
    float* a_src = ws + 2 * (size_t)N_NODES * F_DIM; // N*8
    float* a_dst = a_src + (size_t)N_NODES * N_HEADS;
    int* row_st = (int*)(a_dst + (size_t)N_NODES * N_HEADS); // N+1

    row_start_kernel<<<(N_NODES + 256) / 256, 256, 0, stream>>>(edges, row_st);

    // x = relu(x0 @ Wp + bp)
    matmul_kernel<256><<<N_NODES / 16, 256, 0, stream>>>(
        node_states, Wp, bp, x, 256, 32, 1);

    for (int l = 0; l < 2; ++l) {
        // xt = x @ Wk[l] (heads concatenated)
        matmul_kernel<256><<<N_NODES / 16, 256, 0, stream>>>(
            x, Wk + (size_t)l * N_HEADS * F_DIM * N_UNITS, nullptr, xt, 32,
            8192, 0);
        alpha_kernel<<<N_NODES, 256, 0, stream>>>(
            xt, Wa + (size_t)l * N_HEADS * 64, a_src, a_dst);
        edge_kernel<<<N_NODES, 256, 0, stream>>>(edges, ew, row_st, xt, a_src,
                                                 a_dst, x);
    }

    // out = x @ Wo + bo
    matmul_kernel<64><<<N_NODES / 16, 256, 0, stream>>>(
        x, Wo, bo, out, 64, 32, 0);
}

// Round 2
// 1013.727 us; speedup vs baseline: 1.0631x; 1.0631x over previous
//
#include <hip/hip_runtime.h>
#include <hip/hip_bf16.h>
#include <math.h>

#define N_NODES 50000
#define F_DIM 256
#define NE 1000000
#define N_HEADS 8
#define N_UNITS 32
#define OUT_DIM 64

// ---------------------------------------------------------------------------
// row_start[i] = lower_bound(src, i); src is sorted, so edges of node i are
// [row_start[i], row_start[i+1]).
// ---------------------------------------------------------------------------
__global__ void row_start_kernel(const int* __restrict__ edges,
                                 int* __restrict__ row_start) {
    int i = blockIdx.x * blockDim.x + threadIdx.x;
    if (i > N_NODES) return;
    if (i == N_NODES) { row_start[N_NODES] = NE; return; }
    int lo = 0, hi = NE;
    while (lo < hi) {
        int mid = (lo + hi) >> 1;
        if (edges[2 * mid] < i) lo = mid + 1; else hi = mid;
    }
    row_start[i] = lo;
}

// ---------------------------------------------------------------------------
// Y[N x M] = X[N x 256] @ W + bias (optional), optional relu, fp32 or bf16 out.
// W addressing: W[k][col] at W[k*strideK + (col>>5)*strideH + (col&31)]
// Block: 256 threads, 16 rows x M cols, each thread 4 cols x RPT rows.
// ---------------------------------------------------------------------------
template <int M, bool BF16OUT>
__global__ __launch_bounds__(256) void matmul_kernel(
    const float* __restrict__ X, const float* __restrict__ W,
    const float* __restrict__ bias, float* __restrict__ Y,
    __hip_bfloat16* __restrict__ Y16, int strideK, int strideH,
    int relu_flag) {
    constexpr int RB = 16;            // rows per block
    constexpr int CG = M / 4;         // thread-groups across cols
    constexpr int G = 256 / CG;       // row groups
    constexpr int RPT = RB / G;       // rows per thread
    __shared__ float xs[256][20];     // [k][r], pad keeps 16B align, spreads banks

    const int tid = threadIdx.x;
    const long row0 = (long)blockIdx.x * RB;

    // stage + transpose X tile: k = tid, r = it  (coalesced global reads)
#pragma unroll
    for (int it = 0; it < RB; ++it) {
        xs[tid][it] = X[(row0 + it) * F_DIM + tid];
    }
    __syncthreads();

    const int col0 = (tid % CG) * 4;
    const int rg = tid / CG;
    const int r0 = rg * RPT;
    const float* wp = W + (col0 >> 5) * strideH + (col0 & 31);

    float acc[RPT][4];
#pragma unroll
    for (int j = 0; j < RPT; ++j)
#pragma unroll
        for (int c = 0; c < 4; ++c) acc[j][c] = 0.f;

#pragma unroll 4
    for (int k = 0; k < F_DIM; ++k) {
        const float4 w4 = *(const float4*)(wp + (long)k * strideK);
        float xv[RPT];
#pragma unroll
        for (int j = 0; j < RPT; ++j) xv[j] = xs[k][r0 + j];
#pragma unroll
        for (int j = 0; j < RPT; ++j) {
            acc[j][0] += xv[j] * w4.x;
            acc[j][1] += xv[j] * w4.y;
            acc[j][2] += xv[j] * w4.z;
            acc[j][3] += xv[j] * w4.w;
        }
    }

    float b[4] = {0.f, 0.f, 0.f, 0.f};
    if (bias) {
#pragma unroll
        for (int c = 0; c < 4; ++c) b[c] = bias[col0 + c];
    }
#pragma unroll
    for (int j = 0; j < RPT; ++j) {
        float4 o;
        o.x = acc[j][0] + b[0];
        o.y = acc[j][1] + b[1];
        o.z = acc[j][2] + b[2];
        o.w = acc[j][3] + b[3];
        if (relu_flag) {
            o.x = fmaxf(o.x, 0.f); o.y = fmaxf(o.y, 0.f);
            o.z = fmaxf(o.z, 0.f); o.w = fmaxf(o.w, 0.f);
        }
        const long idx = (row0 + r0 + j) * M + col0;
        if constexpr (BF16OUT) {
            __hip_bfloat16 tmp[4];
            tmp[0] = __float2bfloat16(o.x);
            tmp[1] = __float2bfloat16(o.y);
            tmp[2] = __float2bfloat16(o.z);
            tmp[3] = __float2bfloat16(o.w);
            uint2 pk;
            __builtin_memcpy(&pk, tmp, 8);
            *(uint2*)(&Y16[idx]) = pk;
        } else {
            *(float4*)(&Y[idx]) = o;
        }
    }
}

// ---------------------------------------------------------------------------
// alpha_src[i,h] = xt[i, 32h:32h+32] . Wa_l[h, 0:32]
// alpha_dst[i,h] = xt[i, 32h:32h+32] . Wa_l[h, 32:64]
// ---------------------------------------------------------------------------
__global__ __launch_bounds__(256) void alpha_kernel(
    const __hip_bfloat16* __restrict__ xt16, const float* __restrict__ Wa_l,
    float* __restrict__ a_src, float* __restrict__ a_dst) {
    const int i = blockIdx.x;
    const int tid = threadIdx.x;
    const int h = tid >> 5, u = tid & 31;
    const float v = __bfloat162float(xt16[(long)i * F_DIM + tid]);
    float p1 = v * Wa_l[h * 64 + u];
    float p2 = v * Wa_l[h * 64 + 32 + u];
#pragma unroll
    for (int off = 16; off > 0; off >>= 1) {
        p1 += __shfl_down(p1, off, 32);
        p2 += __shfl_down(p2, off, 32);
    }
    if (u == 0) {
        a_src[i * N_HEADS + h] = p1;
        a_dst[i * N_HEADS + h] = p2;
    }
}

// ---------------------------------------------------------------------------
// s[e,h] = exp(clip(leaky_relu((a_src[src_e,h]+a_dst[dst_e,h])*ew_e), -2, 2))
// one thread per (edge, head); fully coalesced store.
// ---------------------------------------------------------------------------
__global__ __launch_bounds__(256) void score_kernel(
    const int* __restrict__ edges, const float* __restrict__ ew,
    const float* __restrict__ a_src, const float* __restrict__ a_dst,
    float* __restrict__ sbuf) {
    const long idx = (long)blockIdx.x * 256 + threadIdx.x;
    if (idx >= (long)NE * N_HEADS) return;
    const int e = (int)(idx >> 3);
    const int h = (int)(idx & 7);
    const int sn = edges[2 * e];
    const int dn = edges[2 * e + 1];
    const float w = ew[e];
    float sp = (a_src[sn * N_HEADS + h] + a_dst[dn * N_HEADS + h]) * w;
    sp = (sp >= 0.f) ? sp : 0.2f * sp;       // leaky_relu(0.2)
    sp = fminf(fmaxf(sp, -2.f), 2.f);        // clip
    sbuf[idx] = __expf(sp);
}

// ---------------------------------------------------------------------------
// Per-node aggregation. 2 nodes per block; 128 threads per node; each thread
// handles 2 features (one dword of bf16 xt row).
//   acc = sum_e xt16[dst_e]*s[e,h] ; ssum = sum_e s[e,h]
//   x[i] += relu(acc/ssum)
// ---------------------------------------------------------------------------
__global__ __launch_bounds__(256) void edge_kernel(
    const int* __restrict__ edges, const float* __restrict__ sbuf,
    const int* __restrict__ row_start,
    const __hip_bfloat16* __restrict__ xt16, float* __restrict__ x) {
    const int tid = threadIdx.x;
    const int node = blockIdx.x * 2 + (tid >> 7);
    const int t = tid & 127;          // feature-pair index within node
    const int h = t >> 4;             // head of features {2t, 2t+1}
    const int e0 = row_start[node], e1 = row_start[node + 1];
    const uint* __restrict__ xb = (const uint*)xt16;  // 2 bf16 per dword

    float acc0 = 0.f, acc1 = 0.f, ssum = 0.f;
    for (int e = e0; e < e1; ++e) {
        const int d = edges[2 * e + 1];
        const float s = sbuf[e * 8 + h];
        const uint u = xb[d * 128 + t];
        const float f0 = __uint_as_float(u << 16);        // feature 2t
        const float f1 = __uint_as_float(u & 0xffff0000u);// feature 2t+1
        acc0 = fmaf(f0, s, acc0);
        acc1 = fmaf(f1, s, acc1);
        ssum += s;
    }
    const float inv = (e1 > e0) ? (1.0f / ssum) : 0.f;    // empty segment -> 0
    const float v0 = fmaxf(acc0 * inv, 0.f);
    const float v1 = fmaxf(acc1 * inv, 0.f);
    float2* xp = (float2*)(x + (long)node * F_DIM + 2 * t);
    float2 cur = *xp;
    cur.x += v0;
    cur.y += v1;
    *xp = cur;
}

// ---------------------------------------------------------------------------
extern "C" void kernel_launch(void* const* d_in, const int* in_sizes, int n_in,
                              void* d_out, int out_size, void* d_ws,
                              size_t ws_size, hipStream_t stream) {
    const float* node_states = (const float*)d_in[0];  // (1,N,256)
    const int* edges = (const int*)d_in[1];            // (1,E,2) [src,dst]
    const float* ew = (const float*)d_in[2];           // (1,E)
    /* d_in[3] pos_cls: unused by reference */
    const float* Wp = (const float*)d_in[4];           // (256,256)
    const float* bp = (const float*)d_in[5];           // (256,)
    const float* Wk = (const float*)d_in[6];           // (2,8,256,32)
    const float* Wa = (const float*)d_in[7];           // (2,8,64,1)
    const float* Wo = (const float*)d_in[8];           // (256,64)
    const float* bo = (const float*)d_in[9];           // (64,)
    float* out = (float*)d_out;                        // (1,N,64)

    char* ws = (char*)d_ws;
    float* x = (float*)ws;                        ws += (size_t)N_NODES * F_DIM * 4;   // 51.2 MB
    __hip_bfloat16* xt16 = (__hip_bfloat16*)ws;   ws += (size_t)N_NODES * F_DIM * 2;   // 25.6 MB
    float* sbuf = (float*)ws;                     ws += (size_t)NE * N_HEADS * 4;      // 32 MB
    float* a_src = (float*)ws;                    ws += (size_t)N_NODES * N_HEADS * 4; // 1.6 MB
    float* a_dst = (float*)ws;                    ws += (size_t)N_NODES * N_HEADS * 4; // 1.6 MB
    int* row_st = (int*)ws;                       /* N+1 ints */

    row_start_kernel<<<(N_NODES + 256) / 256, 256, 0, stream>>>(edges, row_st);

    // x = relu(x0 @ Wp + bp)  (fp32 out)
    matmul_kernel<256, false><<<N_NODES / 16, 256, 0, stream>>>(
        node_states, Wp, bp, x, nullptr, 256, 32, 1);

    for (int l = 0; l < 2; ++l) {
        // xt16 = bf16(x @ Wk[l]) (heads concatenated)
        matmul_kernel<256, true><<<N_NODES / 16, 256, 0, stream>>>(
            x, Wk + (size_t)l * N_HEADS * F_DIM * N_UNITS, nullptr, nullptr,
            xt16, 32, 8192, 0);
        alpha_kernel<<<N_NODES, 256, 0, stream>>>(
            xt16, Wa + (size_t)l * N_HEADS * 64, a_src, a_dst);
        score_kernel<<<(NE * N_HEADS + 255) / 256, 256, 0, stream>>>(
            edges, ew, a_src, a_dst, sbuf);
        edge_kernel<<<N_NODES / 2, 256, 0, stream>>>(edges, sbuf, row_st, xt16,
                                                     x);
    }

    // out = x @ Wo + bo  (fp32)
    matmul_kernel<64, false><<<N_NODES / 16, 256, 0, stream>>>(
        x, Wo, bo, out, nullptr, 64, 32, 0);
}

// Round 3
// 553.370 us; speedup vs baseline: 1.9476x; 1.8319x over previous
//
#include <hip/hip_runtime.h>
#include <hip/hip_bf16.h>
#include <math.h>

#define N_NODES 50000
#define F_DIM 256
#define NE 1000000
#define N_HEADS 8
#define M_PAD 50048   // 128-row padded

typedef __attribute__((ext_vector_type(8))) short short8;   // 8 bf16 = 4 VGPRs
typedef __attribute__((ext_vector_type(4))) float floatx4;

__device__ __forceinline__ void load16_lds(const void* g, void* l) {
    __builtin_amdgcn_global_load_lds(
        (const __attribute__((address_space(1))) unsigned int*)(unsigned long long)g,
        (__attribute__((address_space(3))) unsigned int*)(unsigned int)(unsigned long long)l,
        16, 0, 0);
}

__device__ __forceinline__ unsigned int pack2bf(float a, float b) {
    __hip_bfloat16 t0 = __float2bfloat16(a), t1 = __float2bfloat16(b);
    unsigned short u0, u1;
    __builtin_memcpy(&u0, &t0, 2);
    __builtin_memcpy(&u1, &t1, 2);
    return (unsigned int)u0 | ((unsigned int)u1 << 16);
}

// ---------------------------------------------------------------------------
// row_start[i] = lower_bound(src, i)
// ---------------------------------------------------------------------------
__global__ void row_start_kernel(const int* __restrict__ edges,
                                 int* __restrict__ row_start) {
    int i = blockIdx.x * blockDim.x + threadIdx.x;
    if (i > N_NODES) return;
    if (i == N_NODES) { row_start[N_NODES] = NE; return; }
    int lo = 0, hi = NE;
    while (lo < hi) {
        int mid = (lo + hi) >> 1;
        if (edges[2 * mid] < i) lo = mid + 1; else hi = mid;
    }
    row_start[i] = lo;
}

// ---------------------------------------------------------------------------
// weight conversion: BT[n][k] = bf16(W[k][n]) layouts
// ---------------------------------------------------------------------------
__global__ void conv_wp_kernel(const float* __restrict__ Wp,
                               __hip_bfloat16* __restrict__ out) {
    int idx = blockIdx.x * 256 + threadIdx.x;  // 65536 = [n][k]
    int n = idx >> 8, k = idx & 255;
    out[idx] = __float2bfloat16(Wp[k * 256 + n]);
}
__global__ void conv_wk_kernel(const float* __restrict__ Wk,
                               __hip_bfloat16* __restrict__ out) {
    int idx = blockIdx.x * 256 + threadIdx.x;  // 131072 = [l][n][k]
    int l = idx >> 16, n = (idx >> 8) & 255, k = idx & 255;
    int h = n >> 5, u = n & 31;
    out[idx] = __float2bfloat16(Wk[(((l * 8 + h) * 256) + k) * 32 + u]);
}
__global__ __launch_bounds__(256) void conv_x_kernel(
    const float* __restrict__ X, __hip_bfloat16* __restrict__ out) {
    const size_t i = ((size_t)blockIdx.x * 256 + threadIdx.x) * 4;
    const float4 v = *(const float4*)(X + i);
    uint2 pk;
    pk.x = pack2bf(v.x, v.y);
    pk.y = pack2bf(v.z, v.w);
    *(uint2*)((unsigned short*)out + i) = pk;
}

// ---------------------------------------------------------------------------
// MFMA GEMM: Y[M x 256] = A16[M x 256] @ B (BT given as [256 n][256 k] bf16)
// 128x128 block tile, 4 waves (2x2), 16x16x32 bf16 MFMA, operands swapped so
// lane holds C[m = lane&15][n0+(lane>>4)*4 .. +3] -> packed stores.
// ---------------------------------------------------------------------------
template <bool BIAS_RELU, bool WRITE_F32>
__global__ __launch_bounds__(256) void gemm_mfma(
    const __hip_bfloat16* __restrict__ A16, const __hip_bfloat16* __restrict__ BT,
    const float* __restrict__ bias, __hip_bfloat16* __restrict__ Y16,
    float* __restrict__ Yf) {
    __shared__ __align__(16) short lA[128 * 32];
    __shared__ __align__(16) short lB[128 * 32];
    const int tid = threadIdx.x;
    const int row0 = blockIdx.x * 128;
    const int n0 = blockIdx.y * 128;
    const int w = tid >> 6, l = tid & 63;
    const int wr = w >> 1, wc = w & 1;

    const __hip_bfloat16* gA = A16 + (size_t)(row0 + (tid >> 2)) * 256 + (tid & 3) * 8;
    const __hip_bfloat16* gB = BT + (size_t)(n0 + (tid >> 2)) * 256 + (tid & 3) * 8;
    short* dA = lA + tid * 8;
    short* dB = lB + tid * 8;

    floatx4 acc[4][4] = {};

    const short* pa = lA + (wr * 64 + (l & 15)) * 32 + (l >> 4) * 8;
    const short* pb = lB + (wc * 64 + (l & 15)) * 32 + (l >> 4) * 8;

    for (int kk = 0; kk < 8; ++kk) {
        const int ko = kk * 32;
        load16_lds(gA + ko, dA);
        load16_lds(gA + 64 * 256 + ko, dA + 256 * 8);
        load16_lds(gB + ko, dB);
        load16_lds(gB + 64 * 256 + ko, dB + 256 * 8);
        __syncthreads();   // drains vmcnt before barrier (compiler-emitted)
        short8 af[4], bf[4];
#pragma unroll
        for (int t = 0; t < 4; ++t) {
            af[t] = *(const short8*)(pa + t * 16 * 32);
            bf[t] = *(const short8*)(pb + t * 16 * 32);
        }
#pragma unroll
        for (int mt = 0; mt < 4; ++mt)
#pragma unroll
            for (int nt = 0; nt < 4; ++nt)
                acc[mt][nt] = __builtin_amdgcn_mfma_f32_16x16x32_bf16(
                    bf[nt], af[mt], acc[mt][nt], 0, 0, 0);
        __syncthreads();
    }

    const int m_base = row0 + wr * 64 + (l & 15);
    const int n_base = n0 + wc * 64 + ((l >> 4) << 2);
#pragma unroll
    for (int mt = 0; mt < 4; ++mt) {
        const int m = m_base + mt * 16;
        if (m >= N_NODES) continue;
#pragma unroll
        for (int nt = 0; nt < 4; ++nt) {
            const int n = n_base + nt * 16;
            floatx4 v = acc[mt][nt];
            if (BIAS_RELU) {
                const float4 bb = *(const float4*)(bias + n);
                v.x = fmaxf(v.x + bb.x, 0.f);
                v.y = fmaxf(v.y + bb.y, 0.f);
                v.z = fmaxf(v.z + bb.z, 0.f);
                v.w = fmaxf(v.w + bb.w, 0.f);
            }
            uint2 pk;
            pk.x = pack2bf(v.x, v.y);
            pk.y = pack2bf(v.z, v.w);
            *(uint2*)((unsigned short*)Y16 + (size_t)m * 256 + n) = pk;
            if (WRITE_F32) {
                float4 o = {v.x, v.y, v.z, v.w};
                *(float4*)(Yf + (size_t)m * 256 + n) = o;
            }
        }
    }
}

// ---------------------------------------------------------------------------
// SIMT fp32 matmul kept for the final (256 -> 64) projection.
// ---------------------------------------------------------------------------
template <int M>
__global__ __launch_bounds__(256) void matmul_kernel(
    const float* __restrict__ X, const float* __restrict__ W,
    const float* __restrict__ bias, float* __restrict__ Y, int strideK,
    int strideH) {
    constexpr int RB = 16;
    constexpr int CG = M / 4;
    constexpr int G = 256 / CG;
    constexpr int RPT = RB / G;
    __shared__ float xs[256][20];

    const int tid = threadIdx.x;
    const long row0 = (long)blockIdx.x * RB;
#pragma unroll
    for (int it = 0; it < RB; ++it) xs[tid][it] = X[(row0 + it) * F_DIM + tid];
    __syncthreads();

    const int col0 = (tid % CG) * 4;
    const int r0 = (tid / CG) * RPT;
    const float* wp = W + (col0 >> 5) * strideH + (col0 & 31);

    float acc[RPT][4];
#pragma unroll
    for (int j = 0; j < RPT; ++j)
#pragma unroll
        for (int c = 0; c < 4; ++c) acc[j][c] = 0.f;

#pragma unroll 4
    for (int k = 0; k < F_DIM; ++k) {
        const float4 w4 = *(const float4*)(wp + (long)k * strideK);
        float xv[RPT];
#pragma unroll
        for (int j = 0; j < RPT; ++j) xv[j] = xs[k][r0 + j];
#pragma unroll
        for (int j = 0; j < RPT; ++j) {
            acc[j][0] += xv[j] * w4.x;
            acc[j][1] += xv[j] * w4.y;
            acc[j][2] += xv[j] * w4.z;
            acc[j][3] += xv[j] * w4.w;
        }
    }
    float b[4];
#pragma unroll
    for (int c = 0; c < 4; ++c) b[c] = bias[col0 + c];
#pragma unroll
    for (int j = 0; j < RPT; ++j) {
        float4 o = {acc[j][0] + b[0], acc[j][1] + b[1], acc[j][2] + b[2],
                    acc[j][3] + b[3]};
        *(float4*)(&Y[(row0 + r0 + j) * M + col0]) = o;
    }
}

// ---------------------------------------------------------------------------
// alpha: per-node attention scalars
// ---------------------------------------------------------------------------
__global__ __launch_bounds__(256) void alpha_kernel(
    const __hip_bfloat16* __restrict__ xt16, const float* __restrict__ Wa_l,
    float* __restrict__ a_src, float* __restrict__ a_dst) {
    const int i = blockIdx.x;
    const int tid = threadIdx.x;
    const int h = tid >> 5, u = tid & 31;
    const float v = __bfloat162float(xt16[(long)i * F_DIM + tid]);
    float p1 = v * Wa_l[h * 64 + u];
    float p2 = v * Wa_l[h * 64 + 32 + u];
#pragma unroll
    for (int off = 16; off > 0; off >>= 1) {
        p1 += __shfl_down(p1, off, 32);
        p2 += __shfl_down(p2, off, 32);
    }
    if (u == 0) {
        a_src[i * N_HEADS + h] = p1;
        a_dst[i * N_HEADS + h] = p2;
    }
}

// ---------------------------------------------------------------------------
// edge scores: s[e,h]
// ---------------------------------------------------------------------------
__global__ __launch_bounds__(256) void score_kernel(
    const int* __restrict__ edges, const float* __restrict__ ew,
    const float* __restrict__ a_src, const float* __restrict__ a_dst,
    float* __restrict__ sbuf) {
    const long idx = (long)blockIdx.x * 256 + threadIdx.x;
    if (idx >= (long)NE * N_HEADS) return;
    const int e = (int)(idx >> 3);
    const int h = (int)(idx & 7);
    const int sn = edges[2 * e];
    const int dn = edges[2 * e + 1];
    const float w = ew[e];
    float sp = (a_src[sn * N_HEADS + h] + a_dst[dn * N_HEADS + h]) * w;
    sp = (sp >= 0.f) ? sp : 0.2f * sp;
    sp = fminf(fmaxf(sp, -2.f), 2.f);
    sbuf[idx] = __expf(sp);
}

// ---------------------------------------------------------------------------
// per-node aggregation: 1 wave per node, lane = 4 features, 4-edge unroll.
// x[i] += relu(acc/ssum); optionally refresh bf16 shadow xb16.
// ---------------------------------------------------------------------------
#define ACC4(u, s)                                          \
    {                                                       \
        a0 = fmaf(__uint_as_float((u).x << 16), s, a0);     \
        a1 = fmaf(__uint_as_float((u).x & 0xffff0000u), s, a1); \
        a2 = fmaf(__uint_as_float((u).y << 16), s, a2);     \
        a3 = fmaf(__uint_as_float((u).y & 0xffff0000u), s, a3); \
    }

__global__ __launch_bounds__(256) void edge_kernel(
    const int* __restrict__ edges, const float* __restrict__ sbuf,
    const int* __restrict__ row_start, const __hip_bfloat16* __restrict__ xt16,
    float* __restrict__ x, __hip_bfloat16* __restrict__ xb16, int write_xb) {
    const int tid = threadIdx.x;
    const int node = blockIdx.x * 4 + (tid >> 6);
    const int l = tid & 63;
    const int h = l >> 3;
    const int e0 = row_start[node], e1 = row_start[node + 1];
    const uint2* __restrict__ xr = (const uint2*)xt16;  // 64 uint2 per row

    float a0 = 0.f, a1 = 0.f, a2 = 0.f, a3 = 0.f, ssum = 0.f;
    int e = e0;
    for (; e + 4 <= e1; e += 4) {
        const uint2 p0 = *(const uint2*)(edges + 2 * e);
        const uint2 p1 = *(const uint2*)(edges + 2 * e + 2);
        const uint2 p2 = *(const uint2*)(edges + 2 * e + 4);
        const uint2 p3 = *(const uint2*)(edges + 2 * e + 6);
        const float s0 = sbuf[e * 8 + h];
        const float s1 = sbuf[e * 8 + 8 + h];
        const float s2 = sbuf[e * 8 + 16 + h];
        const float s3 = sbuf[e * 8 + 24 + h];
        const uint2 u0 = xr[(size_t)p0.y * 64 + l];
        const uint2 u1 = xr[(size_t)p1.y * 64 + l];
        const uint2 u2 = xr[(size_t)p2.y * 64 + l];
        const uint2 u3 = xr[(size_t)p3.y * 64 + l];
        ACC4(u0, s0);
        ACC4(u1, s1);
        ACC4(u2, s2);
        ACC4(u3, s3);
        ssum += (s0 + s1) + (s2 + s3);
    }
    for (; e < e1; ++e) {
        const int d = edges[2 * e + 1];
        const float s = sbuf[e * 8 + h];
        const uint2 u = xr[(size_t)d * 64 + l];
        ACC4(u, s);
        ssum += s;
    }
    const float inv = (e1 > e0) ? 1.f / ssum : 0.f;
    float4* xp = (float4*)(x + (size_t)node * 256 + l * 4);
    float4 c = *xp;
    c.x += fmaxf(a0 * inv, 0.f);
    c.y += fmaxf(a1 * inv, 0.f);
    c.z += fmaxf(a2 * inv, 0.f);
    c.w += fmaxf(a3 * inv, 0.f);
    *xp = c;
    if (write_xb) {
        uint2 pk;
        pk.x = pack2bf(c.x, c.y);
        pk.y = pack2bf(c.z, c.w);
        *(uint2*)((unsigned short*)xb16 + (size_t)node * 256 + l * 4) = pk;
    }
}

// ---------------------------------------------------------------------------
extern "C" void kernel_launch(void* const* d_in, const int* in_sizes, int n_in,
                              void* d_out, int out_size, void* d_ws,
                              size_t ws_size, hipStream_t stream) {
    const float* node_states = (const float*)d_in[0];
    const int* edges = (const int*)d_in[1];
    const float* ew = (const float*)d_in[2];
    const float* Wp = (const float*)d_in[4];
    const float* bp = (const float*)d_in[5];
    const float* Wk = (const float*)d_in[6];
    const float* Wa = (const float*)d_in[7];
    const float* Wo = (const float*)d_in[8];
    const float* bo = (const float*)d_in[9];
    float* out = (float*)d_out;

    char* ws = (char*)d_ws;
    float* x = (float*)ws;                      ws += (size_t)N_NODES * 256 * 4;   // 51.2 MB
    __hip_bfloat16* xb16 = (__hip_bfloat16*)ws; ws += (size_t)M_PAD * 256 * 2;     // 25.6 MB
    __hip_bfloat16* xt16 = (__hip_bfloat16*)ws; ws += (size_t)M_PAD * 256 * 2;     // 25.6 MB
    float* sbuf = (float*)ws;                   ws += (size_t)NE * N_HEADS * 4;    // 32 MB
    float* a_src = (float*)ws;                  ws += (size_t)N_NODES * N_HEADS * 4;
    float* a_dst = (float*)ws;                  ws += (size_t)N_NODES * N_HEADS * 4;
    __hip_bfloat16* wpT = (__hip_bfloat16*)ws;  ws += 65536 * 2;
    __hip_bfloat16* wkT = (__hip_bfloat16*)ws;  ws += 131072 * 2;
    int* row_st = (int*)ws;

    row_start_kernel<<<(N_NODES + 256) / 256, 256, 0, stream>>>(edges, row_st);
    conv_wp_kernel<<<256, 256, 0, stream>>>(Wp, wpT);
    conv_wk_kernel<<<512, 256, 0, stream>>>(Wk, wkT);
    // node_states -> bf16 (staged in xt16, free until first layer GEMM output)
    conv_x_kernel<<<N_NODES * 256 / 4 / 256, 256, 0, stream>>>(node_states, xt16);

    // x = relu(ns @ Wp + bp): fp32 master x + bf16 shadow xb16
    gemm_mfma<true, true><<<dim3((N_NODES + 127) / 128, 2), 256, 0, stream>>>(
        xt16, wpT, bp, xb16, x);

    for (int l = 0; l < 2; ++l) {
        gemm_mfma<false, false><<<dim3((N_NODES + 127) / 128, 2), 256, 0,
                                  stream>>>(xb16, wkT + (size_t)l * 65536,
                                            nullptr, xt16, nullptr);
        alpha_kernel<<<N_NODES, 256, 0, stream>>>(
            xt16, Wa + (size_t)l * N_HEADS * 64, a_src, a_dst);
        score_kernel<<<(NE * N_HEADS + 255) / 256, 256, 0, stream>>>(
            edges, ew, a_src, a_dst, sbuf);
        edge_kernel<<<N_NODES / 4, 256, 0, stream>>>(edges, sbuf, row_st, xt16,
                                                     x, xb16, l == 0 ? 1 : 0);
    }

    matmul_kernel<64><<<N_NODES / 16, 256, 0, stream>>>(x, Wo, bo, out, 64, 32);
}

// Round 4
// 430.048 us; speedup vs baseline: 2.5060x; 1.2868x over previous
//
#include <hip/hip_runtime.h>
#include <hip/hip_bf16.h>
#include <math.h>

#define N_NODES 50000
#define F_DIM 256
#define NE 1000000
#define N_HEADS 8
#define M_PAD 50048   // 128-row padded

typedef __attribute__((ext_vector_type(8))) short short8;   // 8 bf16 = 4 VGPRs
typedef __attribute__((ext_vector_type(4))) float floatx4;

__device__ __forceinline__ void load16_lds(const void* g, void* l) {
    __builtin_amdgcn_global_load_lds(
        (const __attribute__((address_space(1))) unsigned int*)(unsigned long long)g,
        (__attribute__((address_space(3))) unsigned int*)(unsigned int)(unsigned long long)l,
        16, 0, 0);
}

__device__ __forceinline__ unsigned int pack2bf(float a, float b) {
    __hip_bfloat16 t0 = __float2bfloat16(a), t1 = __float2bfloat16(b);
    unsigned short u0, u1;
    __builtin_memcpy(&u0, &t0, 2);
    __builtin_memcpy(&u1, &t1, 2);
    return (unsigned int)u0 | ((unsigned int)u1 << 16);
}

__device__ __forceinline__ float bf_lo(unsigned int u) {
    return __uint_as_float(u << 16);
}
__device__ __forceinline__ float bf_hi(unsigned int u) {
    return __uint_as_float(u & 0xffff0000u);
}

// ---------------------------------------------------------------------------
// row_start[i] = lower_bound(src, i)
// ---------------------------------------------------------------------------
__global__ void row_start_kernel(const int* __restrict__ edges,
                                 int* __restrict__ row_start) {
    int i = blockIdx.x * blockDim.x + threadIdx.x;
    if (i > N_NODES) return;
    if (i == N_NODES) { row_start[N_NODES] = NE; return; }
    int lo = 0, hi = NE;
    while (lo < hi) {
        int mid = (lo + hi) >> 1;
        if (edges[2 * mid] < i) lo = mid + 1; else hi = mid;
    }
    row_start[i] = lo;
}

// ---------------------------------------------------------------------------
// weight conversion kernels: BT[n][k] = bf16(W[k][n])
// ---------------------------------------------------------------------------
__global__ void conv_wp_kernel(const float* __restrict__ Wp,
                               __hip_bfloat16* __restrict__ out) {
    int idx = blockIdx.x * 256 + threadIdx.x;  // 65536 = [n][k]
    int n = idx >> 8, k = idx & 255;
    out[idx] = __float2bfloat16(Wp[k * 256 + n]);
}
__global__ void conv_wk_kernel(const float* __restrict__ Wk,
                               __hip_bfloat16* __restrict__ out) {
    int idx = blockIdx.x * 256 + threadIdx.x;  // 131072 = [l][n][k]
    int l = idx >> 16, n = (idx >> 8) & 255, k = idx & 255;
    int h = n >> 5, u = n & 31;
    out[idx] = __float2bfloat16(Wk[(((l * 8 + h) * 256) + k) * 32 + u]);
}
__global__ void conv_wo_kernel(const float* __restrict__ Wo,
                               __hip_bfloat16* __restrict__ out) {
    int idx = blockIdx.x * 256 + threadIdx.x;  // 16384 = [n(64)][k(256)]
    int n = idx >> 8, k = idx & 255;
    out[idx] = __float2bfloat16(Wo[k * 64 + n]);
}
__global__ __launch_bounds__(256) void conv_x_kernel(
    const float* __restrict__ X, __hip_bfloat16* __restrict__ out) {
    const size_t i = ((size_t)blockIdx.x * 256 + threadIdx.x) * 4;
    const float4 v = *(const float4*)(X + i);
    uint2 pk;
    pk.x = pack2bf(v.x, v.y);
    pk.y = pack2bf(v.z, v.w);
    *(uint2*)((unsigned short*)out + i) = pk;
}

// ---------------------------------------------------------------------------
// MFMA GEMM: Y[M x 256] = A16[M x 256] @ B (BT as [256 n][256 k] bf16)
// 128x128 tile, 4 waves (2x2), 16x16x32 bf16 MFMA, operands swapped so lane
// holds C[m = lane&15 + 16mt][n0 + (lane>>4)*4 + 16nt .. +3] -> packed stores.
// ---------------------------------------------------------------------------
template <bool BIAS_RELU, bool WRITE_F32>
__global__ __launch_bounds__(256) void gemm_mfma(
    const __hip_bfloat16* __restrict__ A16, const __hip_bfloat16* __restrict__ BT,
    const float* __restrict__ bias, __hip_bfloat16* __restrict__ Y16,
    float* __restrict__ Yf) {
    __shared__ __align__(16) short lA[128 * 32];
    __shared__ __align__(16) short lB[128 * 32];
    const int tid = threadIdx.x;
    const int row0 = blockIdx.x * 128;
    const int n0 = blockIdx.y * 128;
    const int w = tid >> 6, l = tid & 63;
    const int wr = w >> 1, wc = w & 1;

    const __hip_bfloat16* gA = A16 + (size_t)(row0 + (tid >> 2)) * 256 + (tid & 3) * 8;
    const __hip_bfloat16* gB = BT + (size_t)(n0 + (tid >> 2)) * 256 + (tid & 3) * 8;
    short* dA = lA + tid * 8;
    short* dB = lB + tid * 8;

    floatx4 acc[4][4] = {};

    const short* pa = lA + (wr * 64 + (l & 15)) * 32 + (l >> 4) * 8;
    const short* pb = lB + (wc * 64 + (l & 15)) * 32 + (l >> 4) * 8;

    for (int kk = 0; kk < 8; ++kk) {
        const int ko = kk * 32;
        load16_lds(gA + ko, dA);
        load16_lds(gA + 64 * 256 + ko, dA + 256 * 8);
        load16_lds(gB + ko, dB);
        load16_lds(gB + 64 * 256 + ko, dB + 256 * 8);
        __syncthreads();
        short8 af[4], bf[4];
#pragma unroll
        for (int t = 0; t < 4; ++t) {
            af[t] = *(const short8*)(pa + t * 16 * 32);
            bf[t] = *(const short8*)(pb + t * 16 * 32);
        }
#pragma unroll
        for (int mt = 0; mt < 4; ++mt)
#pragma unroll
            for (int nt = 0; nt < 4; ++nt)
                acc[mt][nt] = __builtin_amdgcn_mfma_f32_16x16x32_bf16(
                    bf[nt], af[mt], acc[mt][nt], 0, 0, 0);
        __syncthreads();
    }

    const int m_base = row0 + wr * 64 + (l & 15);
    const int n_base = n0 + wc * 64 + ((l >> 4) << 2);
#pragma unroll
    for (int mt = 0; mt < 4; ++mt) {
        const int m = m_base + mt * 16;
        if (m >= N_NODES) continue;
#pragma unroll
        for (int nt = 0; nt < 4; ++nt) {
            const int n = n_base + nt * 16;
            floatx4 v = acc[mt][nt];
            if (BIAS_RELU) {
                const float4 bb = *(const float4*)(bias + n);
                v.x = fmaxf(v.x + bb.x, 0.f);
                v.y = fmaxf(v.y + bb.y, 0.f);
                v.z = fmaxf(v.z + bb.z, 0.f);
                v.w = fmaxf(v.w + bb.w, 0.f);
            }
            uint2 pk;
            pk.x = pack2bf(v.x, v.y);
            pk.y = pack2bf(v.z, v.w);
            *(uint2*)((unsigned short*)Y16 + (size_t)m * 256 + n) = pk;
            if (WRITE_F32) {
                float4 o = {v.x, v.y, v.z, v.w};
                *(float4*)(Yf + (size_t)m * 256 + n) = o;
            }
        }
    }
}

// ---------------------------------------------------------------------------
// Final projection: out[M x 64] = xb16[M x 256] @ Wo + bo  (fp32 out)
// 128x64 tile, 4 waves x 32 rows, same staging/fragment scheme.
// ---------------------------------------------------------------------------
__global__ __launch_bounds__(256) void gemm_mfma_out(
    const __hip_bfloat16* __restrict__ A16, const __hip_bfloat16* __restrict__ BT,
    const float* __restrict__ bias, float* __restrict__ out) {
    __shared__ __align__(16) short lA[128 * 32];
    __shared__ __align__(16) short lB[64 * 32];
    const int tid = threadIdx.x;
    const int row0 = blockIdx.x * 128;
    const int w = tid >> 6, l = tid & 63;

    const __hip_bfloat16* gA = A16 + (size_t)(row0 + (tid >> 2)) * 256 + (tid & 3) * 8;
    const __hip_bfloat16* gB = BT + (size_t)(tid >> 2) * 256 + (tid & 3) * 8;
    short* dA = lA + tid * 8;
    short* dB = lB + tid * 8;   // 256 threads * 8 shorts = exactly 64*32

    floatx4 acc[2][4] = {};

    const short* pa = lA + (w * 32 + (l & 15)) * 32 + (l >> 4) * 8;
    const short* pb = lB + (l & 15) * 32 + (l >> 4) * 8;

    for (int kk = 0; kk < 8; ++kk) {
        const int ko = kk * 32;
        load16_lds(gA + ko, dA);
        load16_lds(gA + 64 * 256 + ko, dA + 256 * 8);
        load16_lds(gB + ko, dB);
        __syncthreads();
        short8 af[2], bf[4];
#pragma unroll
        for (int t = 0; t < 2; ++t) af[t] = *(const short8*)(pa + t * 16 * 32);
#pragma unroll
        for (int t = 0; t < 4; ++t) bf[t] = *(const short8*)(pb + t * 16 * 32);
#pragma unroll
        for (int mt = 0; mt < 2; ++mt)
#pragma unroll
            for (int nt = 0; nt < 4; ++nt)
                acc[mt][nt] = __builtin_amdgcn_mfma_f32_16x16x32_bf16(
                    bf[nt], af[mt], acc[mt][nt], 0, 0, 0);
        __syncthreads();
    }

    const int m_base = row0 + w * 32 + (l & 15);
    const int n_base = (l >> 4) << 2;
#pragma unroll
    for (int mt = 0; mt < 2; ++mt) {
        const int m = m_base + mt * 16;
        if (m >= N_NODES) continue;
#pragma unroll
        for (int nt = 0; nt < 4; ++nt) {
            const int n = n_base + nt * 16;
            const float4 bb = *(const float4*)(bias + n);
            floatx4 v = acc[mt][nt];
            float4 o = {v.x + bb.x, v.y + bb.y, v.z + bb.z, v.w + bb.w};
            *(float4*)(&out[(size_t)m * 64 + n]) = o;
        }
    }
}

// ---------------------------------------------------------------------------
// alpha: per-node attention scalars. 4 nodes/block, lane = 4 features,
// 8-lane reduce per head.
// ---------------------------------------------------------------------------
__global__ __launch_bounds__(256) void alpha_kernel(
    const __hip_bfloat16* __restrict__ xt16, const float* __restrict__ Wa_l,
    float* __restrict__ a_src, float* __restrict__ a_dst) {
    const int tid = threadIdx.x;
    const int node = blockIdx.x * 4 + (tid >> 6);
    const int l = tid & 63;
    const int h = l >> 3;
    const uint2 u = *(const uint2*)((const unsigned short*)xt16 +
                                    (size_t)node * 256 + l * 4);
    const float v0 = bf_lo(u.x), v1 = bf_hi(u.x);
    const float v2 = bf_lo(u.y), v3 = bf_hi(u.y);
    const float4 wa = *(const float4*)(Wa_l + h * 64 + (l & 7) * 4);
    const float4 wb = *(const float4*)(Wa_l + h * 64 + 32 + (l & 7) * 4);
    float p1 = v0 * wa.x + v1 * wa.y + v2 * wa.z + v3 * wa.w;
    float p2 = v0 * wb.x + v1 * wb.y + v2 * wb.z + v3 * wb.w;
#pragma unroll
    for (int off = 4; off > 0; off >>= 1) {
        p1 += __shfl_down(p1, off, 8);
        p2 += __shfl_down(p2, off, 8);
    }
    if ((l & 7) == 0) {
        a_src[node * N_HEADS + h] = p1;
        a_dst[node * N_HEADS + h] = p2;
    }
}

// ---------------------------------------------------------------------------
// edge scores: one thread per edge, all 8 heads; 32B contiguous store.
// ---------------------------------------------------------------------------
__global__ __launch_bounds__(256) void score_kernel(
    const int* __restrict__ edges, const float* __restrict__ ew,
    const float* __restrict__ a_src, const float* __restrict__ a_dst,
    float* __restrict__ sbuf) {
    const int e = blockIdx.x * 256 + threadIdx.x;
    if (e >= NE) return;
    const int2 p = *(const int2*)(edges + 2 * e);
    const float w = ew[e];
    const float4 s0 = *(const float4*)(a_src + (size_t)p.x * 8);
    const float4 s1 = *(const float4*)(a_src + (size_t)p.x * 8 + 4);
    const float4 d0 = *(const float4*)(a_dst + (size_t)p.y * 8);
    const float4 d1 = *(const float4*)(a_dst + (size_t)p.y * 8 + 4);
    float r[8] = {s0.x + d0.x, s0.y + d0.y, s0.z + d0.z, s0.w + d0.w,
                  s1.x + d1.x, s1.y + d1.y, s1.z + d1.z, s1.w + d1.w};
    float4 o0, o1;
    float* op = &o0.x;
#pragma unroll
    for (int h = 0; h < 8; ++h) {
        float sp = r[h] * w;
        sp = (sp >= 0.f) ? sp : 0.2f * sp;    // leaky_relu(0.2)
        sp = fminf(fmaxf(sp, -2.f), 2.f);     // clip
        op[h] = __expf(sp);
    }
    *(float4*)(sbuf + (size_t)e * 8) = o0;
    *(float4*)(sbuf + (size_t)e * 8 + 4) = o1;
}

// ---------------------------------------------------------------------------
// per-node aggregation: 1 wave per node, lane = 4 features, 4-edge unroll.
// x[i] += relu(acc/ssum); refresh bf16 shadow xb16.
// ---------------------------------------------------------------------------
#define ACC4(u, s)                                              \
    {                                                           \
        a0 = fmaf(bf_lo((u).x), s, a0);                         \
        a1 = fmaf(bf_hi((u).x), s, a1);                         \
        a2 = fmaf(bf_lo((u).y), s, a2);                         \
        a3 = fmaf(bf_hi((u).y), s, a3);                         \
    }

__global__ __launch_bounds__(256) void edge_kernel(
    const int* __restrict__ edges, const float* __restrict__ sbuf,
    const int* __restrict__ row_start, const __hip_bfloat16* __restrict__ xt16,
    float* __restrict__ x, __hip_bfloat16* __restrict__ xb16) {
    const int tid = threadIdx.x;
    const int node = blockIdx.x * 4 + (tid >> 6);
    const int l = tid & 63;
    const int h = l >> 3;
    const int e0 = row_start[node], e1 = row_start[node + 1];
    const uint2* __restrict__ xr = (const uint2*)xt16;  // 64 uint2 per row

    float a0 = 0.f, a1 = 0.f, a2 = 0.f, a3 = 0.f, ssum = 0.f;
    int e = e0;
    for (; e + 4 <= e1; e += 4) {
        const uint2 p0 = *(const uint2*)(edges + 2 * e);
        const uint2 p1 = *(const uint2*)(edges + 2 * e + 2);
        const uint2 p2 = *(const uint2*)(edges + 2 * e + 4);
        const uint2 p3 = *(const uint2*)(edges + 2 * e + 6);
        const float s0 = sbuf[e * 8 + h];
        const float s1 = sbuf[e * 8 + 8 + h];
        const float s2 = sbuf[e * 8 + 16 + h];
        const float s3 = sbuf[e * 8 + 24 + h];
        const uint2 u0 = xr[(size_t)p0.y * 64 + l];
        const uint2 u1 = xr[(size_t)p1.y * 64 + l];
        const uint2 u2 = xr[(size_t)p2.y * 64 + l];
        const uint2 u3 = xr[(size_t)p3.y * 64 + l];
        ACC4(u0, s0);
        ACC4(u1, s1);
        ACC4(u2, s2);
        ACC4(u3, s3);
        ssum += (s0 + s1) + (s2 + s3);
    }
    for (; e < e1; ++e) {
        const int d = edges[2 * e + 1];
        const float s = sbuf[e * 8 + h];
        const uint2 u = xr[(size_t)d * 64 + l];
        ACC4(u, s);
        ssum += s;
    }
    const float inv = (e1 > e0) ? 1.f / ssum : 0.f;
    float4* xp = (float4*)(x + (size_t)node * 256 + l * 4);
    float4 c = *xp;
    c.x += fmaxf(a0 * inv, 0.f);
    c.y += fmaxf(a1 * inv, 0.f);
    c.z += fmaxf(a2 * inv, 0.f);
    c.w += fmaxf(a3 * inv, 0.f);
    *xp = c;
    uint2 pk;
    pk.x = pack2bf(c.x, c.y);
    pk.y = pack2bf(c.z, c.w);
    *(uint2*)((unsigned short*)xb16 + (size_t)node * 256 + l * 4) = pk;
}

// ---------------------------------------------------------------------------
extern "C" void kernel_launch(void* const* d_in, const int* in_sizes, int n_in,
                              void* d_out, int out_size, void* d_ws,
                              size_t ws_size, hipStream_t stream) {
    const float* node_states = (const float*)d_in[0];
    const int* edges = (const int*)d_in[1];
    const float* ew = (const float*)d_in[2];
    const float* Wp = (const float*)d_in[4];
    const float* bp = (const float*)d_in[5];
    const float* Wk = (const float*)d_in[6];
    const float* Wa = (const float*)d_in[7];
    const float* Wo = (const float*)d_in[8];
    const float* bo = (const float*)d_in[9];
    float* out = (float*)d_out;

    char* ws = (char*)d_ws;
    float* x = (float*)ws;                      ws += (size_t)N_NODES * 256 * 4;   // 51.2 MB
    __hip_bfloat16* xb16 = (__hip_bfloat16*)ws; ws += (size_t)M_PAD * 256 * 2;     // 25.6 MB
    __hip_bfloat16* xt16 = (__hip_bfloat16*)ws; ws += (size_t)M_PAD * 256 * 2;     // 25.6 MB
    float* sbuf = (float*)ws;                   ws += (size_t)NE * N_HEADS * 4;    // 32 MB
    float* a_src = (float*)ws;                  ws += (size_t)N_NODES * N_HEADS * 4;
    float* a_dst = (float*)ws;                  ws += (size_t)N_NODES * N_HEADS * 4;
    __hip_bfloat16* wpT = (__hip_bfloat16*)ws;  ws += 65536 * 2;
    __hip_bfloat16* wkT = (__hip_bfloat16*)ws;  ws += 131072 * 2;
    __hip_bfloat16* woT = (__hip_bfloat16*)ws;  ws += 16384 * 2;
    int* row_st = (int*)ws;

    row_start_kernel<<<(N_NODES + 256) / 256, 256, 0, stream>>>(edges, row_st);
    conv_wp_kernel<<<256, 256, 0, stream>>>(Wp, wpT);
    conv_wk_kernel<<<512, 256, 0, stream>>>(Wk, wkT);
    conv_wo_kernel<<<64, 256, 0, stream>>>(Wo, woT);
    // node_states -> bf16 (staged in xt16, free until first layer GEMM output)
    conv_x_kernel<<<N_NODES * 256 / 4 / 256, 256, 0, stream>>>(node_states, xt16);

    // x = relu(ns @ Wp + bp): fp32 master x + bf16 shadow xb16
    gemm_mfma<true, true><<<dim3((N_NODES + 127) / 128, 2), 256, 0, stream>>>(
        xt16, wpT, bp, xb16, x);

    for (int l = 0; l < 2; ++l) {
        gemm_mfma<false, false><<<dim3((N_NODES + 127) / 128, 2), 256, 0,
                                  stream>>>(xb16, wkT + (size_t)l * 65536,
                                            nullptr, xt16, nullptr);
        alpha_kernel<<<N_NODES / 4, 256, 0, stream>>>(
            xt16, Wa + (size_t)l * N_HEADS * 64, a_src, a_dst);
        score_kernel<<<(NE + 255) / 256, 256, 0, stream>>>(edges, ew, a_src,
                                                           a_dst, sbuf);
        edge_kernel<<<N_NODES / 4, 256, 0, stream>>>(edges, sbuf, row_st, xt16,
                                                     x, xb16);
    }

    // out = x @ Wo + bo (bf16 MFMA, fp32 store)
    gemm_mfma_out<<<(N_NODES + 127) / 128, 256, 0, stream>>>(xb16, woT, bo, out);
}

// Round 5
// 407.487 us; speedup vs baseline: 2.6448x; 1.0554x over previous
//
#include <hip/hip_runtime.h>
#include <hip/hip_bf16.h>
#include <math.h>

#define N_NODES 50000
#define F_DIM 256
#define NE 1000000
#define N_HEADS 8
#define M_PAD 50048   // 128-row padded

typedef __attribute__((ext_vector_type(8))) short short8;   // 8 bf16 = 4 VGPRs
typedef __attribute__((ext_vector_type(4))) float floatx4;

__device__ __forceinline__ void load16_lds(const void* g, void* l) {
    __builtin_amdgcn_global_load_lds(
        (const __attribute__((address_space(1))) unsigned int*)(unsigned long long)g,
        (__attribute__((address_space(3))) unsigned int*)(unsigned int)(unsigned long long)l,
        16, 0, 0);
}

__device__ __forceinline__ unsigned int pack2bf(float a, float b) {
    __hip_bfloat16 t0 = __float2bfloat16(a), t1 = __float2bfloat16(b);
    unsigned short u0, u1;
    __builtin_memcpy(&u0, &t0, 2);
    __builtin_memcpy(&u1, &t1, 2);
    return (unsigned int)u0 | ((unsigned int)u1 << 16);
}

__device__ __forceinline__ float bf_lo(unsigned int u) {
    return __uint_as_float(u << 16);
}
__device__ __forceinline__ float bf_hi(unsigned int u) {
    return __uint_as_float(u & 0xffff0000u);
}

// ---------------------------------------------------------------------------
// row_start[i] = lower_bound(src, i)
// ---------------------------------------------------------------------------
__global__ void row_start_kernel(const int* __restrict__ edges,
                                 int* __restrict__ row_start) {
    int i = blockIdx.x * blockDim.x + threadIdx.x;
    if (i > N_NODES) return;
    if (i == N_NODES) { row_start[N_NODES] = NE; return; }
    int lo = 0, hi = NE;
    while (lo < hi) {
        int mid = (lo + hi) >> 1;
        if (edges[2 * mid] < i) lo = mid + 1; else hi = mid;
    }
    row_start[i] = lo;
}

// ---------------------------------------------------------------------------
// merged weight conversion: blocks [0,256) Wp, [256,768) Wk, [768,832) Wo
// all produce BT[n][k] = bf16(W[k][n]) layouts
// ---------------------------------------------------------------------------
__global__ void conv_w_kernel(const float* __restrict__ Wp,
                              const float* __restrict__ Wk,
                              const float* __restrict__ Wo,
                              __hip_bfloat16* __restrict__ wpT,
                              __hip_bfloat16* __restrict__ wkT,
                              __hip_bfloat16* __restrict__ woT) {
    const int b = blockIdx.x;
    if (b < 256) {
        int idx = b * 256 + threadIdx.x;           // 65536 = [n][k]
        int n = idx >> 8, k = idx & 255;
        wpT[idx] = __float2bfloat16(Wp[k * 256 + n]);
    } else if (b < 768) {
        int idx = (b - 256) * 256 + threadIdx.x;   // 131072 = [l][n][k]
        int l = idx >> 16, n = (idx >> 8) & 255, k = idx & 255;
        int h = n >> 5, u = n & 31;
        wkT[idx] = __float2bfloat16(Wk[(((l * 8 + h) * 256) + k) * 32 + u]);
    } else {
        int idx = (b - 768) * 256 + threadIdx.x;   // 16384 = [n(64)][k(256)]
        int n = idx >> 8, k = idx & 255;
        woT[idx] = __float2bfloat16(Wo[k * 64 + n]);
    }
}

__global__ __launch_bounds__(256) void conv_x_kernel(
    const float* __restrict__ X, __hip_bfloat16* __restrict__ out) {
    const size_t i = ((size_t)blockIdx.x * 256 + threadIdx.x) * 4;
    const float4 v = *(const float4*)(X + i);
    uint2 pk;
    pk.x = pack2bf(v.x, v.y);
    pk.y = pack2bf(v.z, v.w);
    *(uint2*)((unsigned short*)out + i) = pk;
}

// ---------------------------------------------------------------------------
// MFMA GEMM: Y[M x 256] = A16[M x 256] @ B (BT as [256 n][256 k] bf16)
// 128x128 tile, 4 waves (2x2), 16x16x32 bf16 MFMA, operands swapped so lane
// holds C[m = lane&15 + 16mt][n0 + (lane>>4)*4 + 16nt .. +3] -> packed stores.
// ---------------------------------------------------------------------------
template <bool BIAS_RELU, bool WRITE_F32>
__global__ __launch_bounds__(256) void gemm_mfma(
    const __hip_bfloat16* __restrict__ A16, const __hip_bfloat16* __restrict__ BT,
    const float* __restrict__ bias, __hip_bfloat16* __restrict__ Y16,
    float* __restrict__ Yf) {
    __shared__ __align__(16) short lA[128 * 32];
    __shared__ __align__(16) short lB[128 * 32];
    const int tid = threadIdx.x;
    const int row0 = blockIdx.x * 128;
    const int n0 = blockIdx.y * 128;
    const int w = tid >> 6, l = tid & 63;
    const int wr = w >> 1, wc = w & 1;

    const __hip_bfloat16* gA = A16 + (size_t)(row0 + (tid >> 2)) * 256 + (tid & 3) * 8;
    const __hip_bfloat16* gB = BT + (size_t)(n0 + (tid >> 2)) * 256 + (tid & 3) * 8;
    short* dA = lA + tid * 8;
    short* dB = lB + tid * 8;

    floatx4 acc[4][4] = {};

    const short* pa = lA + (wr * 64 + (l & 15)) * 32 + (l >> 4) * 8;
    const short* pb = lB + (wc * 64 + (l & 15)) * 32 + (l >> 4) * 8;

    for (int kk = 0; kk < 8; ++kk) {
        const int ko = kk * 32;
        load16_lds(gA + ko, dA);
        load16_lds(gA + 64 * 256 + ko, dA + 256 * 8);
        load16_lds(gB + ko, dB);
        load16_lds(gB + 64 * 256 + ko, dB + 256 * 8);
        __syncthreads();
        short8 af[4], bf[4];
#pragma unroll
        for (int t = 0; t < 4; ++t) {
            af[t] = *(const short8*)(pa + t * 16 * 32);
            bf[t] = *(const short8*)(pb + t * 16 * 32);
        }
#pragma unroll
        for (int mt = 0; mt < 4; ++mt)
#pragma unroll
            for (int nt = 0; nt < 4; ++nt)
                acc[mt][nt] = __builtin_amdgcn_mfma_f32_16x16x32_bf16(
                    bf[nt], af[mt], acc[mt][nt], 0, 0, 0);
        __syncthreads();
    }

    const int m_base = row0 + wr * 64 + (l & 15);
    const int n_base = n0 + wc * 64 + ((l >> 4) << 2);
#pragma unroll
    for (int mt = 0; mt < 4; ++mt) {
        const int m = m_base + mt * 16;
        if (m >= N_NODES) continue;
#pragma unroll
        for (int nt = 0; nt < 4; ++nt) {
            const int n = n_base + nt * 16;
            floatx4 v = acc[mt][nt];
            if (BIAS_RELU) {
                const float4 bb = *(const float4*)(bias + n);
                v.x = fmaxf(v.x + bb.x, 0.f);
                v.y = fmaxf(v.y + bb.y, 0.f);
                v.z = fmaxf(v.z + bb.z, 0.f);
                v.w = fmaxf(v.w + bb.w, 0.f);
            }
            uint2 pk;
            pk.x = pack2bf(v.x, v.y);
            pk.y = pack2bf(v.z, v.w);
            *(uint2*)((unsigned short*)Y16 + (size_t)m * 256 + n) = pk;
            if (WRITE_F32) {
                float4 o = {v.x, v.y, v.z, v.w};
                *(float4*)(Yf + (size_t)m * 256 + n) = o;
            }
        }
    }
}

// ---------------------------------------------------------------------------
// Final projection: out[M x 64] = xb16[M x 256] @ Wo + bo  (fp32 out)
// ---------------------------------------------------------------------------
__global__ __launch_bounds__(256) void gemm_mfma_out(
    const __hip_bfloat16* __restrict__ A16, const __hip_bfloat16* __restrict__ BT,
    const float* __restrict__ bias, float* __restrict__ out) {
    __shared__ __align__(16) short lA[128 * 32];
    __shared__ __align__(16) short lB[64 * 32];
    const int tid = threadIdx.x;
    const int row0 = blockIdx.x * 128;
    const int w = tid >> 6, l = tid & 63;

    const __hip_bfloat16* gA = A16 + (size_t)(row0 + (tid >> 2)) * 256 + (tid & 3) * 8;
    const __hip_bfloat16* gB = BT + (size_t)(tid >> 2) * 256 + (tid & 3) * 8;
    short* dA = lA + tid * 8;
    short* dB = lB + tid * 8;   // 256 threads * 8 shorts = exactly 64*32

    floatx4 acc[2][4] = {};

    const short* pa = lA + (w * 32 + (l & 15)) * 32 + (l >> 4) * 8;
    const short* pb = lB + (l & 15) * 32 + (l >> 4) * 8;

    for (int kk = 0; kk < 8; ++kk) {
        const int ko = kk * 32;
        load16_lds(gA + ko, dA);
        load16_lds(gA + 64 * 256 + ko, dA + 256 * 8);
        load16_lds(gB + ko, dB);
        __syncthreads();
        short8 af[2], bf[4];
#pragma unroll
        for (int t = 0; t < 2; ++t) af[t] = *(const short8*)(pa + t * 16 * 32);
#pragma unroll
        for (int t = 0; t < 4; ++t) bf[t] = *(const short8*)(pb + t * 16 * 32);
#pragma unroll
        for (int mt = 0; mt < 2; ++mt)
#pragma unroll
            for (int nt = 0; nt < 4; ++nt)
                acc[mt][nt] = __builtin_amdgcn_mfma_f32_16x16x32_bf16(
                    bf[nt], af[mt], acc[mt][nt], 0, 0, 0);
        __syncthreads();
    }

    const int m_base = row0 + w * 32 + (l & 15);
    const int n_base = (l >> 4) << 2;
#pragma unroll
    for (int mt = 0; mt < 2; ++mt) {
        const int m = m_base + mt * 16;
        if (m >= N_NODES) continue;
#pragma unroll
        for (int nt = 0; nt < 4; ++nt) {
            const int n = n_base + nt * 16;
            const float4 bb = *(const float4*)(bias + n);
            floatx4 v = acc[mt][nt];
            float4 o = {v.x + bb.x, v.y + bb.y, v.z + bb.z, v.w + bb.w};
            *(float4*)(&out[(size_t)m * 64 + n]) = o;
        }
    }
}

// ---------------------------------------------------------------------------
// alpha: per-node attention scalars. 4 nodes/block, lane = 4 features.
// ---------------------------------------------------------------------------
__global__ __launch_bounds__(256) void alpha_kernel(
    const __hip_bfloat16* __restrict__ xt16, const float* __restrict__ Wa_l,
    float* __restrict__ a_src, float* __restrict__ a_dst) {
    const int tid = threadIdx.x;
    const int node =
        __builtin_amdgcn_readfirstlane(blockIdx.x * 4 + (tid >> 6));
    const int l = tid & 63;
    const int h = l >> 3;
    const uint2 u = *(const uint2*)((const unsigned short*)xt16 +
                                    (size_t)node * 256 + l * 4);
    const float v0 = bf_lo(u.x), v1 = bf_hi(u.x);
    const float v2 = bf_lo(u.y), v3 = bf_hi(u.y);
    const float4 wa = *(const float4*)(Wa_l + h * 64 + (l & 7) * 4);
    const float4 wb = *(const float4*)(Wa_l + h * 64 + 32 + (l & 7) * 4);
    float p1 = v0 * wa.x + v1 * wa.y + v2 * wa.z + v3 * wa.w;
    float p2 = v0 * wb.x + v1 * wb.y + v2 * wb.z + v3 * wb.w;
#pragma unroll
    for (int off = 4; off > 0; off >>= 1) {
        p1 += __shfl_down(p1, off, 8);
        p2 += __shfl_down(p2, off, 8);
    }
    if ((l & 7) == 0) {
        a_src[node * N_HEADS + h] = p1;
        a_dst[node * N_HEADS + h] = p2;
    }
}

// ---------------------------------------------------------------------------
// fused score + aggregation: 1 wave per node, lane = 4 features, 4-edge
// unroll. Score computed in-wave from a_src (uniform) + a_dst gather (1.6 MB
// table, L2-resident).  x[i] += relu(acc/ssum); refresh bf16 shadow xb16.
// WRITE_X=false in the last layer (fp32 x is dead there).
// ---------------------------------------------------------------------------
__device__ __forceinline__ float edge_score(float asrc, float ad, float w) {
    float sp = (asrc + ad) * w;
    sp = (sp >= 0.f) ? sp : 0.2f * sp;    // leaky_relu(0.2)
    sp = fminf(fmaxf(sp, -2.f), 2.f);     // clip
    return __expf(sp);
}

#define ACC4(u, s)                                              \
    {                                                           \
        a0 = fmaf(bf_lo((u).x), s, a0);                         \
        a1 = fmaf(bf_hi((u).x), s, a1);                         \
        a2 = fmaf(bf_lo((u).y), s, a2);                         \
        a3 = fmaf(bf_hi((u).y), s, a3);                         \
    }

template <bool WRITE_X>
__global__ __launch_bounds__(256) void edge_kernel(
    const int* __restrict__ edges, const float* __restrict__ ew,
    const int* __restrict__ row_start, const __hip_bfloat16* __restrict__ xt16,
    const float* __restrict__ a_src, const float* __restrict__ a_dst,
    float* __restrict__ x, __hip_bfloat16* __restrict__ xb16) {
    const int tid = threadIdx.x;
    const int node =
        __builtin_amdgcn_readfirstlane(blockIdx.x * 4 + (tid >> 6));
    const int l = tid & 63;
    const int h = l >> 3;
    const float asrc = a_src[node * N_HEADS + h];
    const int e0 = row_start[node], e1 = row_start[node + 1];
    const uint2* __restrict__ xr = (const uint2*)xt16;  // 64 uint2 per row

    float a0 = 0.f, a1 = 0.f, a2 = 0.f, a3 = 0.f, ssum = 0.f;
    int e = e0;
    for (; e + 4 <= e1; e += 4) {
        const int d0 = edges[2 * e + 1];
        const int d1 = edges[2 * e + 3];
        const int d2 = edges[2 * e + 5];
        const int d3 = edges[2 * e + 7];
        const float w0 = ew[e], w1 = ew[e + 1];
        const float w2 = ew[e + 2], w3 = ew[e + 3];
        const float s0 = edge_score(asrc, a_dst[d0 * N_HEADS + h], w0);
        const float s1 = edge_score(asrc, a_dst[d1 * N_HEADS + h], w1);
        const float s2 = edge_score(asrc, a_dst[d2 * N_HEADS + h], w2);
        const float s3 = edge_score(asrc, a_dst[d3 * N_HEADS + h], w3);
        const uint2 u0 = xr[(size_t)d0 * 64 + l];
        const uint2 u1 = xr[(size_t)d1 * 64 + l];
        const uint2 u2 = xr[(size_t)d2 * 64 + l];
        const uint2 u3 = xr[(size_t)d3 * 64 + l];
        ACC4(u0, s0);
        ACC4(u1, s1);
        ACC4(u2, s2);
        ACC4(u3, s3);
        ssum += (s0 + s1) + (s2 + s3);
    }
    for (; e < e1; ++e) {
        const int d = edges[2 * e + 1];
        const float s = edge_score(asrc, a_dst[d * N_HEADS + h], ew[e]);
        const uint2 u = xr[(size_t)d * 64 + l];
        ACC4(u, s);
        ssum += s;
    }
    const float inv = (e1 > e0) ? 1.f / ssum : 0.f;
    float4* xp = (float4*)(x + (size_t)node * 256 + l * 4);
    float4 c = *xp;
    c.x += fmaxf(a0 * inv, 0.f);
    c.y += fmaxf(a1 * inv, 0.f);
    c.z += fmaxf(a2 * inv, 0.f);
    c.w += fmaxf(a3 * inv, 0.f);
    if (WRITE_X) *xp = c;
    uint2 pk;
    pk.x = pack2bf(c.x, c.y);
    pk.y = pack2bf(c.z, c.w);
    *(uint2*)((unsigned short*)xb16 + (size_t)node * 256 + l * 4) = pk;
}

// ---------------------------------------------------------------------------
extern "C" void kernel_launch(void* const* d_in, const int* in_sizes, int n_in,
                              void* d_out, int out_size, void* d_ws,
                              size_t ws_size, hipStream_t stream) {
    const float* node_states = (const float*)d_in[0];
    const int* edges = (const int*)d_in[1];
    const float* ew = (const float*)d_in[2];
    const float* Wp = (const float*)d_in[4];
    const float* bp = (const float*)d_in[5];
    const float* Wk = (const float*)d_in[6];
    const float* Wa = (const float*)d_in[7];
    const float* Wo = (const float*)d_in[8];
    const float* bo = (const float*)d_in[9];
    float* out = (float*)d_out;

    char* ws = (char*)d_ws;
    float* x = (float*)ws;                      ws += (size_t)N_NODES * 256 * 4;   // 51.2 MB
    __hip_bfloat16* xb16 = (__hip_bfloat16*)ws; ws += (size_t)M_PAD * 256 * 2;     // 25.6 MB
    __hip_bfloat16* xt16 = (__hip_bfloat16*)ws; ws += (size_t)M_PAD * 256 * 2;     // 25.6 MB
    float* a_src = (float*)ws;                  ws += (size_t)N_NODES * N_HEADS * 4;
    float* a_dst = (float*)ws;                  ws += (size_t)N_NODES * N_HEADS * 4;
    __hip_bfloat16* wpT = (__hip_bfloat16*)ws;  ws += 65536 * 2;
    __hip_bfloat16* wkT = (__hip_bfloat16*)ws;  ws += 131072 * 2;
    __hip_bfloat16* woT = (__hip_bfloat16*)ws;  ws += 16384 * 2;
    int* row_st = (int*)ws;

    row_start_kernel<<<(N_NODES + 256) / 256, 256, 0, stream>>>(edges, row_st);
    conv_w_kernel<<<832, 256, 0, stream>>>(Wp, Wk, Wo, wpT, wkT, woT);
    // node_states -> bf16 (staged in xt16, free until first layer GEMM output)
    conv_x_kernel<<<N_NODES * 256 / 4 / 256, 256, 0, stream>>>(node_states, xt16);

    // x = relu(ns @ Wp + bp): fp32 master x + bf16 shadow xb16
    gemm_mfma<true, true><<<dim3((N_NODES + 127) / 128, 2), 256, 0, stream>>>(
        xt16, wpT, bp, xb16, x);

    // layer 0: keeps fp32 x up to date (layer 1 needs the residual master)
    gemm_mfma<false, false><<<dim3((N_NODES + 127) / 128, 2), 256, 0, stream>>>(
        xb16, wkT, nullptr, xt16, nullptr);
    alpha_kernel<<<N_NODES / 4, 256, 0, stream>>>(xt16, Wa, a_src, a_dst);
    edge_kernel<true><<<N_NODES / 4, 256, 0, stream>>>(
        edges, ew, row_st, xt16, a_src, a_dst, x, xb16);

    // layer 1: fp32 x write is dead (final GEMM reads xb16 only)
    gemm_mfma<false, false><<<dim3((N_NODES + 127) / 128, 2), 256, 0, stream>>>(
        xb16, wkT + 65536, nullptr, xt16, nullptr);
    alpha_kernel<<<N_NODES / 4, 256, 0, stream>>>(xt16, Wa + 512, a_src, a_dst);
    edge_kernel<false><<<N_NODES / 4, 256, 0, stream>>>(
        edges, ew, row_st, xt16, a_src, a_dst, x, xb16);

    // out = x @ Wo + bo (bf16 MFMA, fp32 store)
    gemm_mfma_out<<<(N_NODES + 127) / 128, 256, 0, stream>>>(xb16, woT, bo, out);
}